// Round 15
// baseline (371.707 us; speedup 1.0000x reference)
//
#include <hip/hip_runtime.h>
#include <math.h>

#define N_NODES 50000
#define NE      800000
#define NEL     (NE + N_NODES)   // edges incl. self-loops
#define NL      8
#define LDHB    288    // hbuf bf16 row stride: 256 GAT out + 8 labels + pad(0)
#define KP0     160    // layer0 Kpad (136 -> 160)
#define KP1     288    // layers1/2 + final Kpad (264 -> 288)
#define NBLK    196    // ceil(N/256) for scan
#define EDGEBLK ((NEL + 255) / 256)
#define HB_BLKS ((N_NODES * 36 + 255) / 256)   // hbuf init items (8 bf16 each)
#define TR_BLKS 97                             // 64x64 transpose tiles (12+20+20+45)
#define MB2     782    // layer GEMM grid (391 M-tiles x 2 col-blocks)

typedef __attribute__((ext_vector_type(8))) short bf16x8;
typedef __attribute__((ext_vector_type(4))) float f32x4;
typedef __attribute__((ext_vector_type(2))) float f32x2;

__device__ __forceinline__ float elu_f(float x) { return x > 0.f ? x : __expf(x) - 1.f; }
__device__ __forceinline__ float bl(unsigned u) { return __uint_as_float(u << 16); }
__device__ __forceinline__ float bh(unsigned u) { return __uint_as_float(u & 0xffff0000u); }
__device__ __forceinline__ unsigned short f2b(float f) {   // RNE f32->bf16
    unsigned u = __float_as_uint(f);
    u += 0x7fff + ((u >> 16) & 1);
    return (unsigned short)(u >> 16);
}
__device__ __forceinline__ unsigned pk2(float lo, float hi) {
    return (unsigned)f2b(lo) | ((unsigned)f2b(hi) << 16);
}
__device__ __forceinline__ unsigned char f2fp8(float f) {   // f32 -> fp8 e4m3 (OCP on gfx950)
    return (unsigned char)(__builtin_amdgcn_cvt_pk_fp8_f32(f, f, 0u, false) & 0xff);
}
// bijective XCD swizzle (m204)
__device__ __forceinline__ int xcd_swizzle(int b, int nwg) {
    int q = nwg >> 3, r = nwg & 7;
    int xcd = b & 7, idx = b >> 3;
    return (xcd < r ? xcd * (q + 1) : r * (q + 1) + (xcd - r) * q) + idx;
}

// -- fused prep: hbuf init + weight transpose + degree histogram + temb --
__global__ void prep_kernel(const float* __restrict__ x, const float* __restrict__ q,
                            unsigned short* __restrict__ hbuf,
                            const float* __restrict__ W0, const float* __restrict__ W1,
                            const float* __restrict__ W2, const float* __restrict__ fw1,
                            unsigned short* __restrict__ wt0, unsigned short* __restrict__ wt1,
                            unsigned short* __restrict__ wt2, unsigned short* __restrict__ fw1t,
                            const int* __restrict__ adj, int* __restrict__ deg,
                            const float* __restrict__ t, const int* __restrict__ nst,
                            const float* __restrict__ tw1, const float* __restrict__ tb1,
                            const float* __restrict__ tw2, const float* __restrict__ tb2,
                            float* __restrict__ temb) {
    __shared__ float tlds[64][65];
    int bid = blockIdx.x, tid = threadIdx.x;
    if (bid < HB_BLKS) {
        int item = bid * 256 + tid;
        if (item >= N_NODES * 36) return;
        int n = item / 36, g = item - n * 36;
        float4 a = make_float4(0.f, 0.f, 0.f, 0.f), b = a;
        if (g < 16) {
            a = *(const float4*)(x + (size_t)n * 128 + g * 8);
            b = *(const float4*)(x + (size_t)n * 128 + g * 8 + 4);
        } else if (g == 16 || g == 32) {
            a = *(const float4*)(q + (size_t)n * 8);
            b = *(const float4*)(q + (size_t)n * 8 + 4);
        }
        uint4 o = make_uint4(pk2(a.x, a.y), pk2(a.z, a.w), pk2(b.x, b.y), pk2(b.z, b.w));
        *(uint4*)(hbuf + (size_t)n * LDHB + g * 8) = o;
        return;
    }
    int j = bid - HB_BLKS;
    if (j < TR_BLKS) {
        const float* W; unsigned short* WT; int K, NN, Kpad, nt;
        if (j < 12)      { W = W0;  WT = wt0;  K = 136; NN = 256; Kpad = KP0; nt = 4; }
        else if (j < 32) { W = W1;  WT = wt1;  K = 264; NN = 256; Kpad = KP1; nt = 4; j -= 12; }
        else if (j < 52) { W = W2;  WT = wt2;  K = 264; NN = 256; Kpad = KP1; nt = 4; j -= 32; }
        else             { W = fw1; WT = fw1t; K = 264; NN = 528; Kpad = KP1; nt = 9; j -= 52; }
        int tk = j / nt, tn = j - tk * nt;
        for (int i = tid; i < 4096; i += 256) {
            int r = i >> 6, c = i & 63;
            int k = tk * 64 + r, n = tn * 64 + c;
            tlds[r][c] = (k < K && n < NN) ? W[(size_t)k * NN + n] : 0.f;
        }
        __syncthreads();
        for (int i = tid; i < 4096; i += 256) {
            int r = i >> 6, c = i & 63;
            int n = tn * 64 + r, kp = tk * 64 + c;
            if (n < NN && kp < Kpad) WT[(size_t)n * Kpad + kp] = f2b(tlds[c][r]);
        }
        return;
    }
    j -= TR_BLKS;
    if (j < EDGEBLK) {
        int e = j * 256 + tid;
        if (e >= NEL) return;
        int d = (e < NE) ? adj[NE + e] : (e - NE);
        atomicAdd(&deg[d], 1);
        return;
    }
    __shared__ float emb[128];
    __shared__ float h1[128];
    float tv = t[0];
    float ns = (float)nst[0];
    float xs = tv / ns * ns * 4.0f;
    if (tid < 64) {
        float fr  = expf((float)tid * (-logf(10000.f) / 63.f));
        float ang = xs * fr;
        emb[tid]      = sinf(ang);
        emb[tid + 64] = cosf(ang);
    }
    __syncthreads();
    if (tid < 128) {
        float a = tb1[tid];
        for (int i = 0; i < 128; ++i) a += emb[i] * tw1[i * 128 + tid];
        h1[tid] = elu_f(a);
    }
    __syncthreads();
    float a = tb2[tid];
    for (int jj = 0; jj < 128; ++jj) a += h1[jj] * tw2[jj * 256 + tid];
    temb[tid] = a;
}

// ================= CSR scan =================
__global__ void scan1_kernel(const int* __restrict__ deg, int* __restrict__ excl,
                             int* __restrict__ bsum) {
    __shared__ int wsum[4];
    int idx = blockIdx.x * 256 + threadIdx.x;
    int lane = threadIdx.x & 63, wid = threadIdx.x >> 6;
    int v = (idx < N_NODES) ? deg[idx] : 0;
    int x = v;
#pragma unroll
    for (int off = 1; off < 64; off <<= 1) {
        int tv2 = __shfl_up(x, off);
        if (lane >= off) x += tv2;
    }
    if (lane == 63) wsum[wid] = x;
    __syncthreads();
    int woff = 0;
    for (int w = 0; w < wid; ++w) woff += wsum[w];
    if (idx < N_NODES) excl[idx] = woff + x - v;
    if (threadIdx.x == 255) bsum[blockIdx.x] = woff + x;
}

__global__ void scan2_kernel(int* __restrict__ bsum, int* __restrict__ boff) {
    __shared__ int wsum[4];
    int tid = threadIdx.x;
    int lane = tid & 63, wid = tid >> 6;
    int v = (tid < NBLK) ? bsum[tid] : 0;
    int x = v;
#pragma unroll
    for (int off = 1; off < 64; off <<= 1) {
        int tv2 = __shfl_up(x, off);
        if (lane >= off) x += tv2;
    }
    if (lane == 63) wsum[wid] = x;
    __syncthreads();
    int woff = 0;
    for (int w = 0; w < wid; ++w) woff += wsum[w];
    if (tid < NBLK) boff[tid] = woff + x - v;
}

__global__ void scan3_kernel(const int* __restrict__ excl, const int* __restrict__ boff,
                             int* __restrict__ rowptr, int* __restrict__ wptr) {
    int idx = blockIdx.x * 256 + threadIdx.x;
    if (idx < N_NODES) {
        int r = excl[idx] + boff[idx >> 8];
        rowptr[idx] = r;
        wptr[idx] = r;
    }
    if (idx == 0) rowptr[N_NODES] = NEL;
}

// ===== MFMA mainloop: gload_lds DMA, double-buffer, counted vmcnt (round-10 exact) =====
template<int NK>
__device__ __forceinline__ void gemm_mainloop(
    const unsigned short* __restrict__ A, int lda,
    const unsigned short* __restrict__ Bt, int ldb,
    int M, int NCm1, int row0, int col0,
    char* lds, f32x4 (&acc)[4][4]) {
    int tid = threadIdx.x;
    int l = tid & 63, w = tid >> 6;
    int wr = w >> 1, wc = w & 1;
    int lr = l & 15, lq = l >> 4;

    int rr0 = w * 16 + (l >> 2);
    int rr1 = 64 + rr0;
    int kg0 = (l & 3) ^ ((rr0 >> 1) & 3);
    int kg1 = (l & 3) ^ ((rr1 >> 1) & 3);
    const unsigned short* gA0 = A + (size_t)min(row0 + rr0, M - 1) * lda + kg0 * 8;
    const unsigned short* gA1 = A + (size_t)min(row0 + rr1, M - 1) * lda + kg1 * 8;
    const unsigned short* gB0 = Bt + (size_t)min(col0 + rr0, NCm1) * ldb + kg0 * 8;
    const unsigned short* gB1 = Bt + (size_t)min(col0 + rr1, NCm1) * ldb + kg1 * 8;
    int la0 = w * 1024;
    int la1 = 4096 + w * 1024;

    int swz = ((lq ^ ((lr >> 1) & 3)) << 4);
    int abase = (wr * 64 + lr) * 64 + swz;
    int bbase = (wc * 64 + lr) * 64 + swz;

#define STAGE(buf, ks)                                                                  \
    {                                                                                   \
        char* base_ = lds + (buf) * 16384;                                              \
        __builtin_amdgcn_global_load_lds(                                               \
            (const __attribute__((address_space(1))) unsigned*)(gA0 + (ks) * 32),       \
            (__attribute__((address_space(3))) unsigned*)(base_ + la0), 16, 0, 0);      \
        __builtin_amdgcn_global_load_lds(                                               \
            (const __attribute__((address_space(1))) unsigned*)(gA1 + (ks) * 32),       \
            (__attribute__((address_space(3))) unsigned*)(base_ + la1), 16, 0, 0);      \
        __builtin_amdgcn_global_load_lds(                                               \
            (const __attribute__((address_space(1))) unsigned*)(gB0 + (ks) * 32),       \
            (__attribute__((address_space(3))) unsigned*)(base_ + 8192 + la0), 16, 0, 0);\
        __builtin_amdgcn_global_load_lds(                                               \
            (const __attribute__((address_space(1))) unsigned*)(gB1 + (ks) * 32),       \
            (__attribute__((address_space(3))) unsigned*)(base_ + 8192 + la1), 16, 0, 0);\
    }

    STAGE(0, 0);
    int cur = 0;
#pragma unroll
    for (int ks = 0; ks < NK; ++ks) {
        if (ks + 1 < NK) {
            STAGE(cur ^ 1, ks + 1);
            asm volatile("s_waitcnt vmcnt(4)" ::: "memory");
        } else {
            asm volatile("s_waitcnt vmcnt(0)" ::: "memory");
        }
        __builtin_amdgcn_s_barrier();
        char* Asc = lds + cur * 16384;
        char* Bsc = Asc + 8192;
        bf16x8 af[4], bfr[4];
#pragma unroll
        for (int m = 0; m < 4; ++m) af[m]  = *(const bf16x8*)(Asc + abase + m * 1024);
#pragma unroll
        for (int n = 0; n < 4; ++n) bfr[n] = *(const bf16x8*)(Bsc + bbase + n * 1024);
#pragma unroll
        for (int m = 0; m < 4; ++m)
#pragma unroll
            for (int n = 0; n < 4; ++n)
                acc[m][n] = __builtin_amdgcn_mfma_f32_16x16x32_bf16(af[m], bfr[n], acc[m][n], 0, 0, 0);
        asm volatile("s_waitcnt lgkmcnt(0)" ::: "memory");
        __builtin_amdgcn_s_barrier();
        cur ^= 1;
    }
#undef STAGE
}

// ===== layer GEMM body: hproj (fp8) + alpha_s/d epilogue; wg in [0, MB2) =====
template<int NK>
__device__ __forceinline__ void layer_gemm_body(
    const unsigned short* __restrict__ A, int lda,
    const unsigned short* __restrict__ Bt, int ldb,
    unsigned char* __restrict__ C8, int M,
    const float* __restrict__ asrc, const float* __restrict__ adst,
    float* __restrict__ alpha_s, float* __restrict__ alpha_d,
    char* lds, int wgid) {
    int wg = xcd_swizzle(wgid, MB2);
    int row0 = (wg >> 1) * 128, col0 = (wg & 1) * 128;
    int lane = threadIdx.x & 63, w = threadIdx.x >> 6;
    int wr = w >> 1, wc = w & 1;
    int lr = lane & 15, lq = lane >> 4;

    f32x4 acc[4][4];
#pragma unroll
    for (int m = 0; m < 4; ++m)
#pragma unroll
        for (int n = 0; n < 4; ++n) acc[m][n] = (f32x4){0.f, 0.f, 0.f, 0.f};

    gemm_mainloop<NK>(A, lda, Bt, ldb, M, 255, row0, col0, lds, acc);

    float asv[4], adv[4];
#pragma unroll
    for (int n = 0; n < 4; ++n) {
        int c = col0 + wc * 64 + n * 16 + lr;
        asv[n] = asrc[c];
        adv[n] = adst[c];
    }
    int h0 = (col0 >> 5) + wc * 2;
    float* aptr = (lr & 2) ? alpha_d : alpha_s;
    int hsel = h0 + (lr & 1);

#pragma unroll
    for (int m = 0; m < 4; ++m) {
        int rbase = row0 + wr * 64 + m * 16 + lq * 4;
#pragma unroll
        for (int i = 0; i < 4; ++i) {
            int row = rbase + i;
            float pAs = acc[m][0][i] * asv[0] + acc[m][1][i] * asv[1];
            float pBs = acc[m][2][i] * asv[2] + acc[m][3][i] * asv[3];
            float pAd = acc[m][0][i] * adv[0] + acc[m][1][i] * adv[1];
            float pBd = acc[m][2][i] * adv[2] + acc[m][3][i] * adv[3];
            float ks_ = (lr & 1) ? pBs : pAs, ss = (lr & 1) ? pAs : pBs;
            float kd_ = (lr & 1) ? pBd : pAd, sd = (lr & 1) ? pAd : pBd;
            float vs = ks_ + __shfl_xor(ss, 1);
            float vd = kd_ + __shfl_xor(sd, 1);
            float kv = (lr & 2) ? vd : vs, sv = (lr & 2) ? vs : vd;
            float vv = kv + __shfl_xor(sv, 2);
            vv += __shfl_xor(vv, 4);
            vv += __shfl_xor(vv, 8);
            if (row < M) {
                if (lr < 4) aptr[row * NL + hsel] = vv;
#pragma unroll
                for (int n = 0; n < 4; ++n) {
                    int col = col0 + wc * 64 + n * 16 + lr;
                    C8[(size_t)row * 256 + col] = f2fp8(acc[m][n][i]);
                }
            }
        }
    }
}

// layer GEMM standalone (layers 1,2)
template<int NK>
__global__ __launch_bounds__(256) void layer_gemm_kernel(
    const unsigned short* __restrict__ A, int lda,
    const unsigned short* __restrict__ Bt, int ldb,
    unsigned char* __restrict__ C8, int M,
    const float* __restrict__ asrc, const float* __restrict__ adst,
    float* __restrict__ alpha_s, float* __restrict__ alpha_d) {
    __shared__ char lds[2][16384];
    layer_gemm_body<NK>(A, lda, Bt, ldb, C8, M, asrc, adst, alpha_s, alpha_d,
                        &lds[0][0], blockIdx.x);
}

// ===== fused layer-0 GEMM + CSR scatter (independent inputs; overlap latency/compute) =====
template<int NK>
__global__ __launch_bounds__(256) void gemm0_scatter_kernel(
    const unsigned short* __restrict__ A, int lda,
    const unsigned short* __restrict__ Bt, int ldb,
    unsigned char* __restrict__ C8, int M,
    const float* __restrict__ asrc, const float* __restrict__ adst,
    float* __restrict__ alpha_s, float* __restrict__ alpha_d,
    const int* __restrict__ adj, int* __restrict__ wptr, int* __restrict__ srcs) {
    __shared__ char lds[2][16384];
    if (blockIdx.x < MB2) {
        layer_gemm_body<NK>(A, lda, Bt, ldb, C8, M, asrc, adst, alpha_s, alpha_d,
                            &lds[0][0], blockIdx.x);
        return;
    }
    int e = (blockIdx.x - MB2) * 256 + threadIdx.x;
    if (e >= NEL) return;
    int s, d;
    if (e < NE) { s = adj[e]; d = adj[NE + e]; }
    else        { s = d = e - NE; }
    int pos = atomicAdd(&wptr[d], 1);
    srcs[pos] = s;
}

// ========== final GEMM fused with output projection (folded 8-shfl reduce) ==========
template<int NK>
__global__ __launch_bounds__(256) void fin_gemm_kernel(
    const unsigned short* __restrict__ A, int lda,
    const unsigned short* __restrict__ Bt, int ldb,
    int M, const float* __restrict__ fb1, const float* __restrict__ w2,
    float* __restrict__ partial) {
    __shared__ char lds[2][16384];
    int wg = xcd_swizzle(blockIdx.x, gridDim.x);
    int by = wg % 5, bx = wg / 5;
    int row0 = bx * 128, col0 = by * 128;
    int lane = threadIdx.x & 63, w = threadIdx.x >> 6;
    int wr = w >> 1, wc = w & 1;
    int lr = lane & 15, lq = lane >> 4;

    f32x4 acc[4][4];
#pragma unroll
    for (int m = 0; m < 4; ++m)
#pragma unroll
        for (int n = 0; n < 4; ++n) acc[m][n] = (f32x4){0.f, 0.f, 0.f, 0.f};

    gemm_mainloop<NK>(A, lda, Bt, ldb, M, 527, row0, col0, &lds[0][0], acc);

    float fbv[4], w2v[4][8];
#pragma unroll
    for (int n = 0; n < 4; ++n) {
        int c = col0 + wc * 64 + n * 16 + lr;
        if (c < 528) {
            fbv[n] = fb1[c];
            float4 wlo = *(const float4*)(w2 + (size_t)c * 8);
            float4 whi = *(const float4*)(w2 + (size_t)c * 8 + 4);
            w2v[n][0] = wlo.x; w2v[n][1] = wlo.y; w2v[n][2] = wlo.z; w2v[n][3] = wlo.w;
            w2v[n][4] = whi.x; w2v[n][5] = whi.y; w2v[n][6] = whi.z; w2v[n][7] = whi.w;
        } else {
            fbv[n] = 0.f;
#pragma unroll
            for (int j = 0; j < 8; ++j) w2v[n][j] = 0.f;
        }
    }
    int jsel = ((lr & 1) << 2) | (lr & 2) | ((lr >> 2) & 1);

    float* pbase = partial + (size_t)(by * 2 + wc) * N_NODES * 8;
#pragma unroll
    for (int m = 0; m < 4; ++m) {
        int rbase = row0 + wr * 64 + m * 16 + lq * 4;
#pragma unroll
        for (int i = 0; i < 4; ++i) {
            int row = rbase + i;
            float pj[8];
#pragma unroll
            for (int j = 0; j < 8; ++j) pj[j] = 0.f;
#pragma unroll
            for (int n = 0; n < 4; ++n) {
                float v = elu_f(acc[m][n][i] + fbv[n]);
#pragma unroll
                for (int j = 0; j < 8; ++j) pj[j] += v * w2v[n][j];
            }
            float v4[4];
#pragma unroll
            for (int j2 = 0; j2 < 4; ++j2) {
                float keep = (lr & 1) ? pj[j2 + 4] : pj[j2];
                float send = (lr & 1) ? pj[j2] : pj[j2 + 4];
                v4[j2] = keep + __shfl_xor(send, 1);
            }
            float v2[2];
#pragma unroll
            for (int j2 = 0; j2 < 2; ++j2) {
                float keep = (lr & 2) ? v4[j2 + 2] : v4[j2];
                float send = (lr & 2) ? v4[j2] : v4[j2 + 2];
                v2[j2] = keep + __shfl_xor(send, 2);
            }
            float keep = (lr & 4) ? v2[1] : v2[0];
            float send = (lr & 4) ? v2[0] : v2[1];
            float v1 = keep + __shfl_xor(send, 4);
            v1 += __shfl_xor(v1, 8);
            if (lr < 8 && row < M) pbase[(size_t)row * 8 + jsel] = v1;
        }
    }
}

// ---------------- reduce 10 partials + fb2 -> out ----------------
__global__ void reduce_kernel(const float* __restrict__ partial, const float* __restrict__ fb2,
                              float* __restrict__ out) {
    int idx = blockIdx.x * 256 + threadIdx.x;
    if (idx >= N_NODES * NL) return;
    float a = fb2[idx & 7];
#pragma unroll
    for (int p = 0; p < 10; ++p) a += partial[(size_t)p * N_NODES * 8 + idx];
    out[idx] = a;
}

// ======= CSR gather (fp8 hproj, packed cvt): wave/node; half-wave edge pairing =======
__global__ __launch_bounds__(256) void gather_kernel(
    const int* __restrict__ rowptr, const int* __restrict__ srcs,
    const float* __restrict__ alpha_s, const float* __restrict__ alpha_d,
    const unsigned char* __restrict__ hproj8, const float* __restrict__ bias,
    const float* __restrict__ temb, unsigned short* __restrict__ h) {
    int node = blockIdx.x * 4 + (threadIdx.x >> 6);
    int lane = threadIdx.x & 63;
    int half = lane >> 5;          // edge parity handled by this half-wave
    int l32  = lane & 31;          // channel block: ch = l32*8 .. +7
    int hd   = l32 >> 2;           // head of these 8 channels
    float ad = alpha_d[node * NL + hd];
    int beg = rowptr[node], end = rowptr[node + 1];
    const uint2* hp2 = (const uint2*)hproj8;   // 32 uint2 (8 fp8 each) per 256-ch row
    float ac0[8], ac1[8];
#pragma unroll
    for (int j = 0; j < 8; ++j) { ac0[j] = 0.f; ac1[j] = 0.f; }
    float den0 = 0.f, den1 = 0.f;
    int i = beg + half;
    for (; i + 2 < end; i += 4) {              // dual chain: edges i and i+2
        int sA = srcs[i], sB = srcs[i + 2];
        float aA = alpha_s[sA * NL + hd] + ad;
        float aB = alpha_s[sB * NL + hd] + ad;
        aA = aA > 0.f ? aA : 0.2f * aA;
        aB = aB > 0.f ? aB : 0.2f * aB;
        float eA = __expf(aA);
        float eB = __expf(aB);
        uint2 hA = hp2[(size_t)sA * 32 + l32];
        uint2 hB = hp2[(size_t)sB * 32 + l32];
        f32x2 a0 = __builtin_amdgcn_cvt_pk_f32_fp8(hA.x, false);
        f32x2 a1 = __builtin_amdgcn_cvt_pk_f32_fp8(hA.x, true);
        f32x2 a2 = __builtin_amdgcn_cvt_pk_f32_fp8(hA.y, false);
        f32x2 a3 = __builtin_amdgcn_cvt_pk_f32_fp8(hA.y, true);
        ac0[0] += eA * a0.x; ac0[1] += eA * a0.y;
        ac0[2] += eA * a1.x; ac0[3] += eA * a1.y;
        ac0[4] += eA * a2.x; ac0[5] += eA * a2.y;
        ac0[6] += eA * a3.x; ac0[7] += eA * a3.y;
        den0 += eA;
        f32x2 b0 = __builtin_amdgcn_cvt_pk_f32_fp8(hB.x, false);
        f32x2 b1 = __builtin_amdgcn_cvt_pk_f32_fp8(hB.x, true);
        f32x2 b2 = __builtin_amdgcn_cvt_pk_f32_fp8(hB.y, false);
        f32x2 b3 = __builtin_amdgcn_cvt_pk_f32_fp8(hB.y, true);
        ac1[0] += eB * b0.x; ac1[1] += eB * b0.y;
        ac1[2] += eB * b1.x; ac1[3] += eB * b1.y;
        ac1[4] += eB * b2.x; ac1[5] += eB * b2.y;
        ac1[6] += eB * b3.x; ac1[7] += eB * b3.y;
        den1 += eB;
    }
    for (; i < end; i += 2) {                  // at most 1 iteration
        int sA = srcs[i];
        float aA = alpha_s[sA * NL + hd] + ad;
        aA = aA > 0.f ? aA : 0.2f * aA;
        float eA = __expf(aA);
        uint2 hA = hp2[(size_t)sA * 32 + l32];
        f32x2 a0 = __builtin_amdgcn_cvt_pk_f32_fp8(hA.x, false);
        f32x2 a1 = __builtin_amdgcn_cvt_pk_f32_fp8(hA.x, true);
        f32x2 a2 = __builtin_amdgcn_cvt_pk_f32_fp8(hA.y, false);
        f32x2 a3 = __builtin_amdgcn_cvt_pk_f32_fp8(hA.y, true);
        ac0[0] += eA * a0.x; ac0[1] += eA * a0.y;
        ac0[2] += eA * a1.x; ac0[3] += eA * a1.y;
        ac0[4] += eA * a2.x; ac0[5] += eA * a2.y;
        ac0[6] += eA * a3.x; ac0[7] += eA * a3.y;
        den0 += eA;
    }
    float den = den0 + den1;
    den += __shfl_xor(den, 32);                // merge half-waves
    float av[8];
#pragma unroll
    for (int j = 0; j < 8; ++j) {
        av[j] = ac0[j] + ac1[j];
        av[j] += __shfl_xor(av[j], 32);
    }
    if (half == 0) {
        float inv = 1.f / den;                 // den>0: self-loop always present
        int c = l32 * 8;
        float4 b0 = *(const float4*)(bias + c);
        float4 b1 = *(const float4*)(bias + c + 4);
        float4 t0 = *(const float4*)(temb + c);
        float4 t1 = *(const float4*)(temb + c + 4);
        uint4 o;
        o.x = pk2(elu_f(av[0] * inv + b0.x + t0.x), elu_f(av[1] * inv + b0.y + t0.y));
        o.y = pk2(elu_f(av[2] * inv + b0.z + t0.z), elu_f(av[3] * inv + b0.w + t0.w));
        o.z = pk2(elu_f(av[4] * inv + b1.x + t1.x), elu_f(av[5] * inv + b1.y + t1.y));
        o.w = pk2(elu_f(av[6] * inv + b1.z + t1.z), elu_f(av[7] * inv + b1.w + t1.w));
        *(uint4*)&h[(size_t)node * LDHB + c] = o;
    }
}

extern "C" void kernel_launch(void* const* d_in, const int* in_sizes, int n_in,
                              void* d_out, int out_size, void* d_ws, size_t ws_size,
                              hipStream_t stream) {
    const float* x   = (const float*)d_in[0];
    const float* q   = (const float*)d_in[1];
    const int*   adj = (const int*)d_in[2];
    const float* t   = (const float*)d_in[3];
    const int*   nst = (const int*)d_in[4];
    const float* W0  = (const float*)d_in[5];
    const float* W1  = (const float*)d_in[6];
    const float* W2  = (const float*)d_in[7];
    const float* att_src = (const float*)d_in[8];
    const float* att_dst = (const float*)d_in[9];
    const float* bias    = (const float*)d_in[10];
    const float* tw1 = (const float*)d_in[11];
    const float* tb1 = (const float*)d_in[12];
    const float* tw2 = (const float*)d_in[13];
    const float* tb2 = (const float*)d_in[14];
    const float* fw1 = (const float*)d_in[15];
    const float* fb1 = (const float*)d_in[16];
    const float* fw2 = (const float*)d_in[17];
    const float* fb2 = (const float*)d_in[18];
    float* out = (float*)d_out;

    // ---- workspace layout (~70 MB) ----
    char* ws = (char*)d_ws;
    unsigned short* hbuf = (unsigned short*)ws;                   // [N,288] bf16
    char* p = ws + (size_t)N_NODES * LDHB * 2;
    unsigned char* hproj8 = (unsigned char*)p;   p += (size_t)N_NODES * 256;        // fp8, 12.8MB
    float* partial = (float*)p;                  p += (size_t)10 * N_NODES * 8 * 4; // 16MB
    float* temb    = (float*)p;                  p += 1024;
    float* alpha_s = (float*)p;                  p += (size_t)N_NODES * NL * 4;
    float* alpha_d = (float*)p;                  p += (size_t)N_NODES * NL * 4;
    unsigned short* wt0  = (unsigned short*)p;   p += (size_t)256 * KP0 * 2;
    unsigned short* wt1  = (unsigned short*)p;   p += (size_t)256 * KP1 * 2;
    unsigned short* wt2  = (unsigned short*)p;   p += (size_t)256 * KP1 * 2;
    unsigned short* fw1t = (unsigned short*)p;   p += (size_t)528 * KP1 * 2;
    int* deg    = (int*)p;                       p += (size_t)N_NODES * 4;
    int* excl   = (int*)p;                       p += (size_t)N_NODES * 4;
    int* bsum   = (int*)p;                       p += 1024;
    int* boff   = (int*)p;                       p += 1024;
    int* rowptr = (int*)p;                       p += (size_t)(N_NODES + 4) * 4;
    int* wptr   = (int*)p;                       p += (size_t)N_NODES * 4;
    int* srcs   = (int*)p;                       p += (size_t)NEL * 4;

    hipMemsetAsync(deg, 0, (size_t)N_NODES * 4, stream);
    prep_kernel<<<HB_BLKS + TR_BLKS + EDGEBLK + 1, 256, 0, stream>>>(
        x, q, hbuf, W0, W1, W2, fw1, wt0, wt1, wt2, fw1t, adj, deg,
        t, nst, tw1, tb1, tw2, tb2, temb);

    scan1_kernel<<<NBLK, 256, 0, stream>>>(deg, excl, bsum);
    scan2_kernel<<<1, 256, 0, stream>>>(bsum, boff);
    scan3_kernel<<<NBLK, 256, 0, stream>>>(excl, boff, rowptr, wptr);

    // layer 0 GEMM fused with scatter (independent inputs -> overlap)
    gemm0_scatter_kernel<KP0 / 32><<<MB2 + EDGEBLK, 256, 0, stream>>>(
        hbuf, LDHB, wt0, KP0, hproj8, N_NODES,
        att_src, att_dst, alpha_s, alpha_d, adj, wptr, srcs);
    gather_kernel<<<(N_NODES + 3) / 4, 256, 0, stream>>>(
        rowptr, srcs, alpha_s, alpha_d, hproj8, bias, temb, hbuf);

    const unsigned short* wts[3] = {wt0, wt1, wt2};
    for (int l = 1; l < 3; ++l) {
        layer_gemm_kernel<KP1 / 32><<<MB2, 256, 0, stream>>>(
            hbuf, LDHB, wts[l], KP1, hproj8, N_NODES,
            att_src + l * 256, att_dst + l * 256, alpha_s, alpha_d);
        gather_kernel<<<(N_NODES + 3) / 4, 256, 0, stream>>>(
            rowptr, srcs, alpha_s, alpha_d, hproj8, bias + l * 256, temb, hbuf);
    }

    int mblocks = (N_NODES + 127) / 128;       // 391
    fin_gemm_kernel<KP1 / 32><<<mblocks * 5, 256, 0, stream>>>(
        hbuf, LDHB, fw1t, KP1, N_NODES, fb1, fw2, partial);
    reduce_kernel<<<(N_NODES * NL + 255) / 256, 256, 0, stream>>>(partial, fb2, out);
}

// Round 16
// 354.460 us; speedup vs baseline: 1.0487x; 1.0487x over previous
//
#include <hip/hip_runtime.h>
#include <math.h>

#define N_NODES 50000
#define NE      800000
#define NEL     (NE + N_NODES)   // edges incl. self-loops
#define NL      8
#define LDHB    288    // hbuf bf16 row stride: 256 GAT out + 8 labels + pad(0)
#define KP0     160    // layer0 Kpad (136 -> 160)
#define KP1     288    // layers1/2 + final Kpad (264 -> 288)
#define NBLK    196    // ceil(N/256) for scan
#define EDGEBLK ((NEL + 255) / 256)
#define HB_BLKS ((N_NODES * 36 + 255) / 256)   // hbuf init items (8 bf16 each)
#define TR_BLKS 97                             // 64x64 transpose tiles (12+20+20+45)
#define MB2     782    // layer GEMM grid (391 M-tiles x 2 col-blocks)

typedef __attribute__((ext_vector_type(8))) short bf16x8;
typedef __attribute__((ext_vector_type(4))) float f32x4;
typedef __attribute__((ext_vector_type(2))) float f32x2;

__device__ __forceinline__ float elu_f(float x) { return x > 0.f ? x : __expf(x) - 1.f; }
__device__ __forceinline__ float bl(unsigned u) { return __uint_as_float(u << 16); }
__device__ __forceinline__ float bh(unsigned u) { return __uint_as_float(u & 0xffff0000u); }
__device__ __forceinline__ unsigned short f2b(float f) {   // RNE f32->bf16
    unsigned u = __float_as_uint(f);
    u += 0x7fff + ((u >> 16) & 1);
    return (unsigned short)(u >> 16);
}
__device__ __forceinline__ unsigned pk2(float lo, float hi) {
    return (unsigned)f2b(lo) | ((unsigned)f2b(hi) << 16);
}
__device__ __forceinline__ unsigned char f2fp8(float f) {   // f32 -> fp8 e4m3 (OCP on gfx950)
    return (unsigned char)(__builtin_amdgcn_cvt_pk_fp8_f32(f, f, 0u, false) & 0xff);
}
// bijective XCD swizzle (m204)
__device__ __forceinline__ int xcd_swizzle(int b, int nwg) {
    int q = nwg >> 3, r = nwg & 7;
    int xcd = b & 7, idx = b >> 3;
    return (xcd < r ? xcd * (q + 1) : r * (q + 1) + (xcd - r) * q) + idx;
}

// -- fused prep: hbuf init + weight transpose + degree histogram + temb --
__global__ void prep_kernel(const float* __restrict__ x, const float* __restrict__ q,
                            unsigned short* __restrict__ hbuf,
                            const float* __restrict__ W0, const float* __restrict__ W1,
                            const float* __restrict__ W2, const float* __restrict__ fw1,
                            unsigned short* __restrict__ wt0, unsigned short* __restrict__ wt1,
                            unsigned short* __restrict__ wt2, unsigned short* __restrict__ fw1t,
                            const int* __restrict__ adj, int* __restrict__ deg,
                            const float* __restrict__ t, const int* __restrict__ nst,
                            const float* __restrict__ tw1, const float* __restrict__ tb1,
                            const float* __restrict__ tw2, const float* __restrict__ tb2,
                            float* __restrict__ temb) {
    __shared__ float tlds[64][65];
    int bid = blockIdx.x, tid = threadIdx.x;
    if (bid < HB_BLKS) {
        int item = bid * 256 + tid;
        if (item >= N_NODES * 36) return;
        int n = item / 36, g = item - n * 36;
        float4 a = make_float4(0.f, 0.f, 0.f, 0.f), b = a;
        if (g < 16) {
            a = *(const float4*)(x + (size_t)n * 128 + g * 8);
            b = *(const float4*)(x + (size_t)n * 128 + g * 8 + 4);
        } else if (g == 16 || g == 32) {
            a = *(const float4*)(q + (size_t)n * 8);
            b = *(const float4*)(q + (size_t)n * 8 + 4);
        }
        uint4 o = make_uint4(pk2(a.x, a.y), pk2(a.z, a.w), pk2(b.x, b.y), pk2(b.z, b.w));
        *(uint4*)(hbuf + (size_t)n * LDHB + g * 8) = o;
        return;
    }
    int j = bid - HB_BLKS;
    if (j < TR_BLKS) {
        const float* W; unsigned short* WT; int K, NN, Kpad, nt;
        if (j < 12)      { W = W0;  WT = wt0;  K = 136; NN = 256; Kpad = KP0; nt = 4; }
        else if (j < 32) { W = W1;  WT = wt1;  K = 264; NN = 256; Kpad = KP1; nt = 4; j -= 12; }
        else if (j < 52) { W = W2;  WT = wt2;  K = 264; NN = 256; Kpad = KP1; nt = 4; j -= 32; }
        else             { W = fw1; WT = fw1t; K = 264; NN = 528; Kpad = KP1; nt = 9; j -= 52; }
        int tk = j / nt, tn = j - tk * nt;
        for (int i = tid; i < 4096; i += 256) {
            int r = i >> 6, c = i & 63;
            int k = tk * 64 + r, n = tn * 64 + c;
            tlds[r][c] = (k < K && n < NN) ? W[(size_t)k * NN + n] : 0.f;
        }
        __syncthreads();
        for (int i = tid; i < 4096; i += 256) {
            int r = i >> 6, c = i & 63;
            int n = tn * 64 + r, kp = tk * 64 + c;
            if (n < NN && kp < Kpad) WT[(size_t)n * Kpad + kp] = f2b(tlds[c][r]);
        }
        return;
    }
    j -= TR_BLKS;
    if (j < EDGEBLK) {
        int e = j * 256 + tid;
        if (e >= NEL) return;
        int d = (e < NE) ? adj[NE + e] : (e - NE);
        atomicAdd(&deg[d], 1);
        return;
    }
    __shared__ float emb[128];
    __shared__ float h1[128];
    float tv = t[0];
    float ns = (float)nst[0];
    float xs = tv / ns * ns * 4.0f;
    if (tid < 64) {
        float fr  = expf((float)tid * (-logf(10000.f) / 63.f));
        float ang = xs * fr;
        emb[tid]      = sinf(ang);
        emb[tid + 64] = cosf(ang);
    }
    __syncthreads();
    if (tid < 128) {
        float a = tb1[tid];
        for (int i = 0; i < 128; ++i) a += emb[i] * tw1[i * 128 + tid];
        h1[tid] = elu_f(a);
    }
    __syncthreads();
    float a = tb2[tid];
    for (int jj = 0; jj < 128; ++jj) a += h1[jj] * tw2[jj * 256 + tid];
    temb[tid] = a;
}

// ================= CSR scan =================
__global__ void scan1_kernel(const int* __restrict__ deg, int* __restrict__ excl,
                             int* __restrict__ bsum) {
    __shared__ int wsum[4];
    int idx = blockIdx.x * 256 + threadIdx.x;
    int lane = threadIdx.x & 63, wid = threadIdx.x >> 6;
    int v = (idx < N_NODES) ? deg[idx] : 0;
    int x = v;
#pragma unroll
    for (int off = 1; off < 64; off <<= 1) {
        int tv2 = __shfl_up(x, off);
        if (lane >= off) x += tv2;
    }
    if (lane == 63) wsum[wid] = x;
    __syncthreads();
    int woff = 0;
    for (int w = 0; w < wid; ++w) woff += wsum[w];
    if (idx < N_NODES) excl[idx] = woff + x - v;
    if (threadIdx.x == 255) bsum[blockIdx.x] = woff + x;
}

__global__ void scan2_kernel(int* __restrict__ bsum, int* __restrict__ boff) {
    __shared__ int wsum[4];
    int tid = threadIdx.x;
    int lane = tid & 63, wid = tid >> 6;
    int v = (tid < NBLK) ? bsum[tid] : 0;
    int x = v;
#pragma unroll
    for (int off = 1; off < 64; off <<= 1) {
        int tv2 = __shfl_up(x, off);
        if (lane >= off) x += tv2;
    }
    if (lane == 63) wsum[wid] = x;
    __syncthreads();
    int woff = 0;
    for (int w = 0; w < wid; ++w) woff += wsum[w];
    if (tid < NBLK) boff[tid] = woff + x - v;
}

__global__ void scan3_kernel(const int* __restrict__ excl, const int* __restrict__ boff,
                             int* __restrict__ rowptr, int* __restrict__ wptr) {
    int idx = blockIdx.x * 256 + threadIdx.x;
    if (idx < N_NODES) {
        int r = excl[idx] + boff[idx >> 8];
        rowptr[idx] = r;
        wptr[idx] = r;
    }
    if (idx == 0) rowptr[N_NODES] = NEL;
}

// ===== MFMA mainloop: gload_lds DMA, double-buffer, counted vmcnt (round-10 exact) =====
template<int NK>
__device__ __forceinline__ void gemm_mainloop(
    const unsigned short* __restrict__ A, int lda,
    const unsigned short* __restrict__ Bt, int ldb,
    int M, int NCm1, int row0, int col0,
    char* lds, f32x4 (&acc)[4][4]) {
    int tid = threadIdx.x;
    int l = tid & 63, w = tid >> 6;
    int wr = w >> 1, wc = w & 1;
    int lr = l & 15, lq = l >> 4;

    int rr0 = w * 16 + (l >> 2);
    int rr1 = 64 + rr0;
    int kg0 = (l & 3) ^ ((rr0 >> 1) & 3);
    int kg1 = (l & 3) ^ ((rr1 >> 1) & 3);
    const unsigned short* gA0 = A + (size_t)min(row0 + rr0, M - 1) * lda + kg0 * 8;
    const unsigned short* gA1 = A + (size_t)min(row0 + rr1, M - 1) * lda + kg1 * 8;
    const unsigned short* gB0 = Bt + (size_t)min(col0 + rr0, NCm1) * ldb + kg0 * 8;
    const unsigned short* gB1 = Bt + (size_t)min(col0 + rr1, NCm1) * ldb + kg1 * 8;
    int la0 = w * 1024;
    int la1 = 4096 + w * 1024;

    int swz = ((lq ^ ((lr >> 1) & 3)) << 4);
    int abase = (wr * 64 + lr) * 64 + swz;
    int bbase = (wc * 64 + lr) * 64 + swz;

#define STAGE(buf, ks)                                                                  \
    {                                                                                   \
        char* base_ = lds + (buf) * 16384;                                              \
        __builtin_amdgcn_global_load_lds(                                               \
            (const __attribute__((address_space(1))) unsigned*)(gA0 + (ks) * 32),       \
            (__attribute__((address_space(3))) unsigned*)(base_ + la0), 16, 0, 0);      \
        __builtin_amdgcn_global_load_lds(                                               \
            (const __attribute__((address_space(1))) unsigned*)(gA1 + (ks) * 32),       \
            (__attribute__((address_space(3))) unsigned*)(base_ + la1), 16, 0, 0);      \
        __builtin_amdgcn_global_load_lds(                                               \
            (const __attribute__((address_space(1))) unsigned*)(gB0 + (ks) * 32),       \
            (__attribute__((address_space(3))) unsigned*)(base_ + 8192 + la0), 16, 0, 0);\
        __builtin_amdgcn_global_load_lds(                                               \
            (const __attribute__((address_space(1))) unsigned*)(gB1 + (ks) * 32),       \
            (__attribute__((address_space(3))) unsigned*)(base_ + 8192 + la1), 16, 0, 0);\
    }

    STAGE(0, 0);
    int cur = 0;
#pragma unroll
    for (int ks = 0; ks < NK; ++ks) {
        if (ks + 1 < NK) {
            STAGE(cur ^ 1, ks + 1);
            asm volatile("s_waitcnt vmcnt(4)" ::: "memory");
        } else {
            asm volatile("s_waitcnt vmcnt(0)" ::: "memory");
        }
        __builtin_amdgcn_s_barrier();
        char* Asc = lds + cur * 16384;
        char* Bsc = Asc + 8192;
        bf16x8 af[4], bfr[4];
#pragma unroll
        for (int m = 0; m < 4; ++m) af[m]  = *(const bf16x8*)(Asc + abase + m * 1024);
#pragma unroll
        for (int n = 0; n < 4; ++n) bfr[n] = *(const bf16x8*)(Bsc + bbase + n * 1024);
#pragma unroll
        for (int m = 0; m < 4; ++m)
#pragma unroll
            for (int n = 0; n < 4; ++n)
                acc[m][n] = __builtin_amdgcn_mfma_f32_16x16x32_bf16(af[m], bfr[n], acc[m][n], 0, 0, 0);
        asm volatile("s_waitcnt lgkmcnt(0)" ::: "memory");
        __builtin_amdgcn_s_barrier();
        cur ^= 1;
    }
#undef STAGE
}

// ===== layer GEMM body: hproj (fp8) + alpha_s/d epilogue; wg in [0, MB2) =====
template<int NK>
__device__ __forceinline__ void layer_gemm_body(
    const unsigned short* __restrict__ A, int lda,
    const unsigned short* __restrict__ Bt, int ldb,
    unsigned char* __restrict__ C8, int M,
    const float* __restrict__ asrc, const float* __restrict__ adst,
    float* __restrict__ alpha_s, float* __restrict__ alpha_d,
    char* lds, int wgid) {
    int wg = xcd_swizzle(wgid, MB2);
    int row0 = (wg >> 1) * 128, col0 = (wg & 1) * 128;
    int lane = threadIdx.x & 63, w = threadIdx.x >> 6;
    int wr = w >> 1, wc = w & 1;
    int lr = lane & 15, lq = lane >> 4;

    f32x4 acc[4][4];
#pragma unroll
    for (int m = 0; m < 4; ++m)
#pragma unroll
        for (int n = 0; n < 4; ++n) acc[m][n] = (f32x4){0.f, 0.f, 0.f, 0.f};

    gemm_mainloop<NK>(A, lda, Bt, ldb, M, 255, row0, col0, lds, acc);

    float asv[4], adv[4];
#pragma unroll
    for (int n = 0; n < 4; ++n) {
        int c = col0 + wc * 64 + n * 16 + lr;
        asv[n] = asrc[c];
        adv[n] = adst[c];
    }
    int h0 = (col0 >> 5) + wc * 2;
    float* aptr = (lr & 2) ? alpha_d : alpha_s;
    int hsel = h0 + (lr & 1);

#pragma unroll
    for (int m = 0; m < 4; ++m) {
        int rbase = row0 + wr * 64 + m * 16 + lq * 4;
#pragma unroll
        for (int i = 0; i < 4; ++i) {
            int row = rbase + i;
            float pAs = acc[m][0][i] * asv[0] + acc[m][1][i] * asv[1];
            float pBs = acc[m][2][i] * asv[2] + acc[m][3][i] * asv[3];
            float pAd = acc[m][0][i] * adv[0] + acc[m][1][i] * adv[1];
            float pBd = acc[m][2][i] * adv[2] + acc[m][3][i] * adv[3];
            float ks_ = (lr & 1) ? pBs : pAs, ss = (lr & 1) ? pAs : pBs;
            float kd_ = (lr & 1) ? pBd : pAd, sd = (lr & 1) ? pAd : pBd;
            float vs = ks_ + __shfl_xor(ss, 1);
            float vd = kd_ + __shfl_xor(sd, 1);
            float kv = (lr & 2) ? vd : vs, sv = (lr & 2) ? vs : vd;
            float vv = kv + __shfl_xor(sv, 2);
            vv += __shfl_xor(vv, 4);
            vv += __shfl_xor(vv, 8);
            if (row < M) {
                if (lr < 4) aptr[row * NL + hsel] = vv;
#pragma unroll
                for (int n = 0; n < 4; ++n) {
                    int col = col0 + wc * 64 + n * 16 + lr;
                    C8[(size_t)row * 256 + col] = f2fp8(acc[m][n][i]);
                }
            }
        }
    }
}

// layer GEMM standalone (layers 1,2)
template<int NK>
__global__ __launch_bounds__(256, 4) void layer_gemm_kernel(
    const unsigned short* __restrict__ A, int lda,
    const unsigned short* __restrict__ Bt, int ldb,
    unsigned char* __restrict__ C8, int M,
    const float* __restrict__ asrc, const float* __restrict__ adst,
    float* __restrict__ alpha_s, float* __restrict__ alpha_d) {
    __shared__ char lds[2][16384];
    layer_gemm_body<NK>(A, lda, Bt, ldb, C8, M, asrc, adst, alpha_s, alpha_d,
                        &lds[0][0], blockIdx.x);
}

// ===== fused CSR scatter + layer-0 GEMM: SCATTER BLOCKS FIRST (latency path starts
// immediately and saturates; GEMM blocks fill CU bubbles behind it) =====
template<int NK>
__global__ __launch_bounds__(256, 4) void gemm0_scatter_kernel(
    const unsigned short* __restrict__ A, int lda,
    const unsigned short* __restrict__ Bt, int ldb,
    unsigned char* __restrict__ C8, int M,
    const float* __restrict__ asrc, const float* __restrict__ adst,
    float* __restrict__ alpha_s, float* __restrict__ alpha_d,
    const int* __restrict__ adj, int* __restrict__ wptr, int* __restrict__ srcs) {
    __shared__ char lds[2][16384];
    if (blockIdx.x < EDGEBLK) {
        int e = blockIdx.x * 256 + threadIdx.x;
        if (e >= NEL) return;
        int s, d;
        if (e < NE) { s = adj[e]; d = adj[NE + e]; }
        else        { s = d = e - NE; }
        int pos = atomicAdd(&wptr[d], 1);
        srcs[pos] = s;
        return;
    }
    layer_gemm_body<NK>(A, lda, Bt, ldb, C8, M, asrc, adst, alpha_s, alpha_d,
                        &lds[0][0], blockIdx.x - EDGEBLK);
}

// ========== final GEMM fused with output projection (folded 8-shfl reduce) ==========
template<int NK>
__global__ __launch_bounds__(256, 4) void fin_gemm_kernel(
    const unsigned short* __restrict__ A, int lda,
    const unsigned short* __restrict__ Bt, int ldb,
    int M, const float* __restrict__ fb1, const float* __restrict__ w2,
    float* __restrict__ partial) {
    __shared__ char lds[2][16384];
    int wg = xcd_swizzle(blockIdx.x, gridDim.x);
    int by = wg % 5, bx = wg / 5;
    int row0 = bx * 128, col0 = by * 128;
    int lane = threadIdx.x & 63, w = threadIdx.x >> 6;
    int wr = w >> 1, wc = w & 1;
    int lr = lane & 15, lq = lane >> 4;

    f32x4 acc[4][4];
#pragma unroll
    for (int m = 0; m < 4; ++m)
#pragma unroll
        for (int n = 0; n < 4; ++n) acc[m][n] = (f32x4){0.f, 0.f, 0.f, 0.f};

    gemm_mainloop<NK>(A, lda, Bt, ldb, M, 527, row0, col0, &lds[0][0], acc);

    float fbv[4], w2v[4][8];
#pragma unroll
    for (int n = 0; n < 4; ++n) {
        int c = col0 + wc * 64 + n * 16 + lr;
        if (c < 528) {
            fbv[n] = fb1[c];
            float4 wlo = *(const float4*)(w2 + (size_t)c * 8);
            float4 whi = *(const float4*)(w2 + (size_t)c * 8 + 4);
            w2v[n][0] = wlo.x; w2v[n][1] = wlo.y; w2v[n][2] = wlo.z; w2v[n][3] = wlo.w;
            w2v[n][4] = whi.x; w2v[n][5] = whi.y; w2v[n][6] = whi.z; w2v[n][7] = whi.w;
        } else {
            fbv[n] = 0.f;
#pragma unroll
            for (int j = 0; j < 8; ++j) w2v[n][j] = 0.f;
        }
    }
    int jsel = ((lr & 1) << 2) | (lr & 2) | ((lr >> 2) & 1);

    float* pbase = partial + (size_t)(by * 2 + wc) * N_NODES * 8;
#pragma unroll
    for (int m = 0; m < 4; ++m) {
        int rbase = row0 + wr * 64 + m * 16 + lq * 4;
#pragma unroll
        for (int i = 0; i < 4; ++i) {
            int row = rbase + i;
            float pj[8];
#pragma unroll
            for (int j = 0; j < 8; ++j) pj[j] = 0.f;
#pragma unroll
            for (int n = 0; n < 4; ++n) {
                float v = elu_f(acc[m][n][i] + fbv[n]);
#pragma unroll
                for (int j = 0; j < 8; ++j) pj[j] += v * w2v[n][j];
            }
            float v4[4];
#pragma unroll
            for (int j2 = 0; j2 < 4; ++j2) {
                float keep = (lr & 1) ? pj[j2 + 4] : pj[j2];
                float send = (lr & 1) ? pj[j2] : pj[j2 + 4];
                v4[j2] = keep + __shfl_xor(send, 1);
            }
            float v2[2];
#pragma unroll
            for (int j2 = 0; j2 < 2; ++j2) {
                float keep = (lr & 2) ? v4[j2 + 2] : v4[j2];
                float send = (lr & 2) ? v4[j2] : v4[j2 + 2];
                v2[j2] = keep + __shfl_xor(send, 2);
            }
            float keep = (lr & 4) ? v2[1] : v2[0];
            float send = (lr & 4) ? v2[0] : v2[1];
            float v1 = keep + __shfl_xor(send, 4);
            v1 += __shfl_xor(v1, 8);
            if (lr < 8 && row < M) pbase[(size_t)row * 8 + jsel] = v1;
        }
    }
}

// ---------------- reduce 10 partials + fb2 -> out ----------------
__global__ void reduce_kernel(const float* __restrict__ partial, const float* __restrict__ fb2,
                              float* __restrict__ out) {
    int idx = blockIdx.x * 256 + threadIdx.x;
    if (idx >= N_NODES * NL) return;
    float a = fb2[idx & 7];
#pragma unroll
    for (int p = 0; p < 10; ++p) a += partial[(size_t)p * N_NODES * 8 + idx];
    out[idx] = a;
}

// ======= CSR gather (fp8 hproj, packed cvt): wave/node; half-wave edge pairing =======
__global__ __launch_bounds__(256) void gather_kernel(
    const int* __restrict__ rowptr, const int* __restrict__ srcs,
    const float* __restrict__ alpha_s, const float* __restrict__ alpha_d,
    const unsigned char* __restrict__ hproj8, const float* __restrict__ bias,
    const float* __restrict__ temb, unsigned short* __restrict__ h) {
    int node = blockIdx.x * 4 + (threadIdx.x >> 6);
    int lane = threadIdx.x & 63;
    int half = lane >> 5;          // edge parity handled by this half-wave
    int l32  = lane & 31;          // channel block: ch = l32*8 .. +7
    int hd   = l32 >> 2;           // head of these 8 channels
    float ad = alpha_d[node * NL + hd];
    int beg = rowptr[node], end = rowptr[node + 1];
    const uint2* hp2 = (const uint2*)hproj8;   // 32 uint2 (8 fp8 each) per 256-ch row
    float ac0[8], ac1[8];
#pragma unroll
    for (int j = 0; j < 8; ++j) { ac0[j] = 0.f; ac1[j] = 0.f; }
    float den0 = 0.f, den1 = 0.f;
    int i = beg + half;
    for (; i + 2 < end; i += 4) {              // dual chain: edges i and i+2
        int sA = srcs[i], sB = srcs[i + 2];
        float aA = alpha_s[sA * NL + hd] + ad;
        float aB = alpha_s[sB * NL + hd] + ad;
        aA = aA > 0.f ? aA : 0.2f * aA;
        aB = aB > 0.f ? aB : 0.2f * aB;
        float eA = __expf(aA);
        float eB = __expf(aB);
        uint2 hA = hp2[(size_t)sA * 32 + l32];
        uint2 hB = hp2[(size_t)sB * 32 + l32];
        f32x2 a0 = __builtin_amdgcn_cvt_pk_f32_fp8(hA.x, false);
        f32x2 a1 = __builtin_amdgcn_cvt_pk_f32_fp8(hA.x, true);
        f32x2 a2 = __builtin_amdgcn_cvt_pk_f32_fp8(hA.y, false);
        f32x2 a3 = __builtin_amdgcn_cvt_pk_f32_fp8(hA.y, true);
        ac0[0] += eA * a0.x; ac0[1] += eA * a0.y;
        ac0[2] += eA * a1.x; ac0[3] += eA * a1.y;
        ac0[4] += eA * a2.x; ac0[5] += eA * a2.y;
        ac0[6] += eA * a3.x; ac0[7] += eA * a3.y;
        den0 += eA;
        f32x2 b0 = __builtin_amdgcn_cvt_pk_f32_fp8(hB.x, false);
        f32x2 b1 = __builtin_amdgcn_cvt_pk_f32_fp8(hB.x, true);
        f32x2 b2 = __builtin_amdgcn_cvt_pk_f32_fp8(hB.y, false);
        f32x2 b3 = __builtin_amdgcn_cvt_pk_f32_fp8(hB.y, true);
        ac1[0] += eB * b0.x; ac1[1] += eB * b0.y;
        ac1[2] += eB * b1.x; ac1[3] += eB * b1.y;
        ac1[4] += eB * b2.x; ac1[5] += eB * b2.y;
        ac1[6] += eB * b3.x; ac1[7] += eB * b3.y;
        den1 += eB;
    }
    for (; i < end; i += 2) {                  // at most 1 iteration
        int sA = srcs[i];
        float aA = alpha_s[sA * NL + hd] + ad;
        aA = aA > 0.f ? aA : 0.2f * aA;
        float eA = __expf(aA);
        uint2 hA = hp2[(size_t)sA * 32 + l32];
        f32x2 a0 = __builtin_amdgcn_cvt_pk_f32_fp8(hA.x, false);
        f32x2 a1 = __builtin_amdgcn_cvt_pk_f32_fp8(hA.x, true);
        f32x2 a2 = __builtin_amdgcn_cvt_pk_f32_fp8(hA.y, false);
        f32x2 a3 = __builtin_amdgcn_cvt_pk_f32_fp8(hA.y, true);
        ac0[0] += eA * a0.x; ac0[1] += eA * a0.y;
        ac0[2] += eA * a1.x; ac0[3] += eA * a1.y;
        ac0[4] += eA * a2.x; ac0[5] += eA * a2.y;
        ac0[6] += eA * a3.x; ac0[7] += eA * a3.y;
        den0 += eA;
    }
    float den = den0 + den1;
    den += __shfl_xor(den, 32);                // merge half-waves
    float av[8];
#pragma unroll
    for (int j = 0; j < 8; ++j) {
        av[j] = ac0[j] + ac1[j];
        av[j] += __shfl_xor(av[j], 32);
    }
    if (half == 0) {
        float inv = 1.f / den;                 // den>0: self-loop always present
        int c = l32 * 8;
        float4 b0 = *(const float4*)(bias + c);
        float4 b1 = *(const float4*)(bias + c + 4);
        float4 t0 = *(const float4*)(temb + c);
        float4 t1 = *(const float4*)(temb + c + 4);
        uint4 o;
        o.x = pk2(elu_f(av[0] * inv + b0.x + t0.x), elu_f(av[1] * inv + b0.y + t0.y));
        o.y = pk2(elu_f(av[2] * inv + b0.z + t0.z), elu_f(av[3] * inv + b0.w + t0.w));
        o.z = pk2(elu_f(av[4] * inv + b1.x + t1.x), elu_f(av[5] * inv + b1.y + t1.y));
        o.w = pk2(elu_f(av[6] * inv + b1.z + t1.z), elu_f(av[7] * inv + b1.w + t1.w));
        *(uint4*)&h[(size_t)node * LDHB + c] = o;
    }
}

extern "C" void kernel_launch(void* const* d_in, const int* in_sizes, int n_in,
                              void* d_out, int out_size, void* d_ws, size_t ws_size,
                              hipStream_t stream) {
    const float* x   = (const float*)d_in[0];
    const float* q   = (const float*)d_in[1];
    const int*   adj = (const int*)d_in[2];
    const float* t   = (const float*)d_in[3];
    const int*   nst = (const int*)d_in[4];
    const float* W0  = (const float*)d_in[5];
    const float* W1  = (const float*)d_in[6];
    const float* W2  = (const float*)d_in[7];
    const float* att_src = (const float*)d_in[8];
    const float* att_dst = (const float*)d_in[9];
    const float* bias    = (const float*)d_in[10];
    const float* tw1 = (const float*)d_in[11];
    const float* tb1 = (const float*)d_in[12];
    const float* tw2 = (const float*)d_in[13];
    const float* tb2 = (const float*)d_in[14];
    const float* fw1 = (const float*)d_in[15];
    const float* fb1 = (const float*)d_in[16];
    const float* fw2 = (const float*)d_in[17];
    const float* fb2 = (const float*)d_in[18];
    float* out = (float*)d_out;

    // ---- workspace layout (~70 MB) ----
    char* ws = (char*)d_ws;
    unsigned short* hbuf = (unsigned short*)ws;                   // [N,288] bf16
    char* p = ws + (size_t)N_NODES * LDHB * 2;
    unsigned char* hproj8 = (unsigned char*)p;   p += (size_t)N_NODES * 256;        // fp8, 12.8MB
    float* partial = (float*)p;                  p += (size_t)10 * N_NODES * 8 * 4; // 16MB
    float* temb    = (float*)p;                  p += 1024;
    float* alpha_s = (float*)p;                  p += (size_t)N_NODES * NL * 4;
    float* alpha_d = (float*)p;                  p += (size_t)N_NODES * NL * 4;
    unsigned short* wt0  = (unsigned short*)p;   p += (size_t)256 * KP0 * 2;
    unsigned short* wt1  = (unsigned short*)p;   p += (size_t)256 * KP1 * 2;
    unsigned short* wt2  = (unsigned short*)p;   p += (size_t)256 * KP1 * 2;
    unsigned short* fw1t = (unsigned short*)p;   p += (size_t)528 * KP1 * 2;
    int* deg    = (int*)p;                       p += (size_t)N_NODES * 4;
    int* excl   = (int*)p;                       p += (size_t)N_NODES * 4;
    int* bsum   = (int*)p;                       p += 1024;
    int* boff   = (int*)p;                       p += 1024;
    int* rowptr = (int*)p;                       p += (size_t)(N_NODES + 4) * 4;
    int* wptr   = (int*)p;                       p += (size_t)N_NODES * 4;
    int* srcs   = (int*)p;                       p += (size_t)NEL * 4;

    hipMemsetAsync(deg, 0, (size_t)N_NODES * 4, stream);
    prep_kernel<<<HB_BLKS + TR_BLKS + EDGEBLK + 1, 256, 0, stream>>>(
        x, q, hbuf, W0, W1, W2, fw1, wt0, wt1, wt2, fw1t, adj, deg,
        t, nst, tw1, tb1, tw2, tb2, temb);

    scan1_kernel<<<NBLK, 256, 0, stream>>>(deg, excl, bsum);
    scan2_kernel<<<1, 256, 0, stream>>>(bsum, boff);
    scan3_kernel<<<NBLK, 256, 0, stream>>>(excl, boff, rowptr, wptr);

    // scatter (first; latency-bound) fused with layer-0 GEMM (fills bubbles)
    gemm0_scatter_kernel<KP0 / 32><<<EDGEBLK + MB2, 256, 0, stream>>>(
        hbuf, LDHB, wt0, KP0, hproj8, N_NODES,
        att_src, att_dst, alpha_s, alpha_d, adj, wptr, srcs);
    gather_kernel<<<(N_NODES + 3) / 4, 256, 0, stream>>>(
        rowptr, srcs, alpha_s, alpha_d, hproj8, bias, temb, hbuf);

    const unsigned short* wts[3] = {wt0, wt1, wt2};
    for (int l = 1; l < 3; ++l) {
        layer_gemm_kernel<KP1 / 32><<<MB2, 256, 0, stream>>>(
            hbuf, LDHB, wts[l], KP1, hproj8, N_NODES,
            att_src + l * 256, att_dst + l * 256, alpha_s, alpha_d);
        gather_kernel<<<(N_NODES + 3) / 4, 256, 0, stream>>>(
            rowptr, srcs, alpha_s, alpha_d, hproj8, bias + l * 256, temb, hbuf);
    }

    int mblocks = (N_NODES + 127) / 128;       // 391
    fin_gemm_kernel<KP1 / 32><<<mblocks * 5, 256, 0, stream>>>(
        hbuf, LDHB, fw1t, KP1, N_NODES, fb1, fw2, partial);
    reduce_kernel<<<(N_NODES * NL + 255) / 256, 256, 0, stream>>>(partial, fb2, out);
}